// Round 17
// baseline (127.370 us; speedup 1.0000x reference)
//
#include <hip/hip_runtime.h>
#include <hip/hip_bf16.h>

typedef unsigned short u16;
typedef __attribute__((ext_vector_type(8))) short bf16x8;
typedef __attribute__((ext_vector_type(8))) short short8;
typedef __attribute__((ext_vector_type(4))) float f32x4;

#define B_ 16
#define CIN 256
#define COUT 256
#define NPIX 4096
#define E_ 8
#define HP 66            // halo-padded width/height
#define PPIX (HP*HP)     // 4356 padded pixels per sample
#define KTOT 2304        // 9 * 256
#define NKT 36           // K-tiles of 64

__device__ __forceinline__ u16 f2bf(float f){
    union { float f; unsigned int u; } v; v.f = f;
    return (u16)((v.u + 0x7FFFu + ((v.u >> 16) & 1u)) >> 16);
}

__device__ __forceinline__ void gload(const u16* g, u16* l){
    __builtin_amdgcn_global_load_lds(
        (const __attribute__((address_space(1))) unsigned int*)g,
        (__attribute__((address_space(3))) unsigned int*)l, 16, 0, 0);
}

// -------- 1) transpose+convert x -> xt2[b][(y+1)*66+(x+1)][cin] bf16,
//            fused pool + border-zero; coalesced uint4 stores + cvt_pk --------
__global__ void k_xt(const float* __restrict__ x, u16* __restrict__ xt2,
                     float* __restrict__ pooled){
    __shared__ float tile[64][65];
    int bid = blockIdx.x;
    int t = threadIdx.x;

    if (bid < 520){
        int gid = bid*256 + t;
        int u4 = gid & 31;
        int pl = gid >> 5;
        if (pl < B_*260){
            int bb = pl / 260;
            int pi = pl - bb*260;
            int yy, xx;
            if (pi < 66)      { yy = 0;  xx = pi; }
            else if (pi < 132){ yy = 65; xx = pi - 66; }
            else { int q = pi - 132; yy = 1 + (q >> 1); xx = (q & 1) ? 65 : 0; }
            uint4 z = {0u,0u,0u,0u};
            *(uint4*)(xt2 + ((size_t)bb*PPIX + yy*HP + xx)*CIN + u4*8) = z;
        }
    }

    int b = bid >> 8, ct = (bid >> 6) & 3, pt = bid & 63;
    int c0 = ct*64, p0 = pt*64;
    #pragma unroll
    for (int iter = 0; iter < 4; ++iter){
        int idx = t*4 + iter*1024;
        int r = idx >> 6, c4 = idx & 63;
        float4 v = *(const float4*)(x + ((size_t)(b*CIN + c0 + r))*NPIX + p0 + c4);
        tile[r][c4+0] = v.x; tile[r][c4+1] = v.y; tile[r][c4+2] = v.z; tile[r][c4+3] = v.w;
        float rs = v.x + v.y + v.z + v.w;
        #pragma unroll
        for (int off = 1; off < 16; off <<= 1) rs += __shfl_xor(rs, off, 64);
        if ((t & 15) == 0) atomicAdd(&pooled[b*CIN + c0 + r], rs);
    }
    __syncthreads();
    #pragma unroll
    for (int iter = 0; iter < 2; ++iter){
        int unit = t + iter*256;
        int g_l = unit & 7, pr = unit >> 3;
        unsigned int d0, d1, d2, d3;
        asm("v_cvt_pk_bf16_f32 %0, %1, %2" : "=v"(d0)
            : "v"(tile[g_l*8+0][pr]), "v"(tile[g_l*8+1][pr]));
        asm("v_cvt_pk_bf16_f32 %0, %1, %2" : "=v"(d1)
            : "v"(tile[g_l*8+2][pr]), "v"(tile[g_l*8+3][pr]));
        asm("v_cvt_pk_bf16_f32 %0, %1, %2" : "=v"(d2)
            : "v"(tile[g_l*8+4][pr]), "v"(tile[g_l*8+5][pr]));
        asm("v_cvt_pk_bf16_f32 %0, %1, %2" : "=v"(d3)
            : "v"(tile[g_l*8+6][pr]), "v"(tile[g_l*8+7][pr]));
        uint4 o; o.x = d0; o.y = d1; o.z = d2; o.w = d3;
        int p = p0 + pr;
        int yy = p >> 6, xx = p & 63;
        *(uint4*)(xt2 + ((size_t)b*PPIX + (yy+1)*HP + (xx+1))*CIN + c0 + g_l*8) = o;
    }
}

// -------- 2) aggregated weights: 576 threads, batch split across two thread groups --------
__global__ __launch_bounds__(576) void k_aggw(
    const float* __restrict__ weight, const float* __restrict__ pooled,
    const float* __restrict__ rw, const float* __restrict__ rb,
    const float* __restrict__ bias,
    u16* __restrict__ aggw, float* __restrict__ aggb)
{
    __shared__ float wls[E_][2304];
    __shared__ float r_s[B_*E_];
    int o = blockIdx.x, t = threadIdx.x;

    if (t < B_*E_){
        int b = t >> 3, e = t & 7;
        const float4* pp = (const float4*)(pooled + b*CIN);
        const float4* wp = (const float4*)(rw + e*CIN);
        float s = 0.f;
        #pragma unroll
        for (int i = 0; i < 64; ++i){
            float4 a = pp[i], c = wp[i];
            s += a.x*c.x + a.y*c.y + a.z*c.z + a.w*c.w;
        }
        s = s * (1.0f/(float)NPIX) + rb[e];
        r_s[t] = 1.0f/(1.0f + __expf(-s));
    }
    #pragma unroll
    for (int e = 0; e < E_; ++e){
        const float4* src = (const float4*)(weight + ((size_t)(e*COUT + o))*2304);
        float4* dst = (float4*)wls[e];
        dst[t] = src[t];
    }
    __syncthreads();

    if (t < B_){
        float s = 0.f;
        #pragma unroll
        for (int e = 0; e < E_; ++e) s += r_s[t*E_+e]*bias[e*COUT+o];
        aggb[t*COUT + o] = s;
    }

    {
        int grp = (t >= 288);
        int u = t - grp*288;
        int tp = u >> 5, cg = u & 31;
        float w[E_][8];
        #pragma unroll
        for (int e = 0; e < E_; ++e)
            #pragma unroll
            for (int j = 0; j < 8; ++j)
                w[e][j] = wls[e][(cg*8 + j)*9 + tp];

        int b0 = grp*8;
        for (int bb = 0; bb < 8; ++bb){
            int b = b0 + bb;
            float acc[8];
            #pragma unroll
            for (int j = 0; j < 8; ++j) acc[j] = 0.f;
            #pragma unroll
            for (int e = 0; e < E_; ++e){
                float r = r_s[b*E_ + e];
                #pragma unroll
                for (int j = 0; j < 8; ++j) acc[j] += r * w[e][j];
            }
            short8 ov;
            #pragma unroll
            for (int jj = 0; jj < 4; ++jj){
                unsigned int d;
                asm("v_cvt_pk_bf16_f32 %0, %1, %2" : "=v"(d) : "v"(acc[2*jj]), "v"(acc[2*jj+1]));
                ov[2*jj]   = (short)(d & 0xFFFF);
                ov[2*jj+1] = (short)(d >> 16);
            }
            *(short8*)(aggw + (((size_t)(b*COUT + o))*9 + tp)*CIN + cg*8) = ov;
        }
    }
}

// -------- 3) k_conv: 128x128 tile, 4 waves, dbuf 64KB -> 2 blocks/CU
//            (cross-block barrier-domain overlap; R4 body, no setprio) --------
__global__ __launch_bounds__(256) void k_conv(
    const u16* __restrict__ aggw, const u16* __restrict__ xt2,
    const float* __restrict__ aggb, float* __restrict__ out)
{
    __shared__ __align__(16) u16 lds[32768];   // 2 buf x (A 128x64 + B 128x64) bf16 = 64KB

    int orig = blockIdx.x;
    int bid = (orig & 7)*128 + (orig >> 3);    // bijective XCD swizzle (1024 % 8 == 0)

    int b  = bid >> 6;          // sample
    int mt = (bid >> 5) & 1;    // M half
    int nt = bid & 31;          // pixel tile (128 px = 2 image rows)
    int m0 = mt << 7;
    int y0 = nt << 1;

    int t = threadIdx.x;
    int lane = t & 63;
    int w = t >> 6;             // wave 0..3
    int wm = (w >> 1) << 6;     // 0 / 64
    int wn = (w & 1) << 6;      // 0 / 64
    int l16 = lane & 15;
    int kh4 = lane >> 4;
    int sw  = l16 & 7;

    // staging: thread t -> row tr = t>>3 (+32*i), slot tc = t&7 holds granule tc^(tr&7)
    int tr = t >> 3;            // 0..31
    int tc = t & 7;
    int sc = tc ^ (tr & 7);

    const u16* aSrc = aggw + (size_t)b*COUT*9*CIN + (size_t)(m0 + tr)*KTOT + sc*8;
    const u16* bSrc = xt2 + ((size_t)b*PPIX + (size_t)y0*HP + tr)*CIN + sc*8;

    f32x4 acc[4][4];
    #pragma unroll
    for (int i = 0; i < 4; ++i)
        #pragma unroll
        for (int j = 0; j < 4; ++j){
            f32x4 z = {0.f,0.f,0.f,0.f};
            acc[i][j] = z;
        }

    auto stage = [&](int kt, int bufn){
        int tap = kt >> 2;
        int c0  = (kt & 3) << 6;
        int kh  = tap / 3, kw = tap - kh*3;
        const u16* a0 = aSrc + tap*CIN + c0;
        const u16* b0 = bSrc + (kh*HP + kw)*CIN + c0;
        u16* dA = lds + bufn*16384 + t*8;
        u16* dB = dA + 8192;
        #pragma unroll
        for (int i = 0; i < 4; ++i)
            gload(a0 + (size_t)i*32*KTOT, dA + i*2048);
        #pragma unroll
        for (int i = 0; i < 4; ++i)
            gload(b0 + (size_t)((i>>1)*HP + (i&1)*32)*CIN, dB + i*2048);
    };

    int ck0 = ((kh4    ) ^ sw) * 8;
    int ck1 = ((kh4 | 4) ^ sw) * 8;

    stage(0, 0);
    __syncthreads();

    int buf = 0;
    #pragma unroll 2
    for (int kt = 0; kt < NKT; ++kt){
        const u16* LA = lds + buf*16384;
        const u16* LB = LA + 8192;

        bf16x8 af[4][2];    // [mf][khalf]
        bf16x8 bfr[4][2];   // [nf][khalf]

        // first half of reads (critical path for cluster 0)
        #pragma unroll
        for (int mf = 0; mf < 4; ++mf){
            int ro = (wm + mf*16 + l16) * 64;
            af[mf][0] = *(const bf16x8*)(LA + ro + ck0);
            af[mf][1] = *(const bf16x8*)(LA + ro + ck1);
        }
        #pragma unroll
        for (int nf = 0; nf < 2; ++nf){
            int ro = (wn + nf*16 + l16) * 64;
            bfr[nf][0] = *(const bf16x8*)(LB + ro + ck0);
            bfr[nf][1] = *(const bf16x8*)(LB + ro + ck1);
        }

        if (kt < NKT-1) stage(kt+1, buf^1);

        #pragma unroll
        for (int nf = 2; nf < 4; ++nf){
            int ro = (wn + nf*16 + l16) * 64;
            bfr[nf][0] = *(const bf16x8*)(LB + ro + ck0);
            bfr[nf][1] = *(const bf16x8*)(LB + ro + ck1);
        }

        #pragma unroll
        for (int mf = 0; mf < 4; ++mf)
            #pragma unroll
            for (int nf = 0; nf < 4; ++nf){
                acc[mf][nf] = __builtin_amdgcn_mfma_f32_16x16x32_bf16(
                    af[mf][0], bfr[nf][0], acc[mf][nf], 0, 0, 0);
                acc[mf][nf] = __builtin_amdgcn_mfma_f32_16x16x32_bf16(
                    af[mf][1], bfr[nf][1], acc[mf][nf], 0, 0, 0);
            }

        __syncthreads();
        buf ^= 1;
    }

    const float* ab = aggb + b*COUT + m0;
    float* outp = out + ((size_t)(b*COUT + m0))*NPIX + nt*128;
    #pragma unroll
    for (int mf = 0; mf < 4; ++mf){
        #pragma unroll
        for (int v = 0; v < 4; ++v){
            int r = wm + mf*16 + (kh4 << 2) + v;
            float bias_r = ab[r];
            float* orow = outp + (size_t)r*NPIX;
            #pragma unroll
            for (int nf = 0; nf < 4; ++nf)
                orow[wn + nf*16 + l16] = acc[mf][nf][v] + bias_r;
        }
    }
}

extern "C" void kernel_launch(void* const* d_in, const int* in_sizes, int n_in,
                              void* d_out, int out_size, void* d_ws, size_t ws_size,
                              hipStream_t stream)
{
    const float* x      = (const float*)d_in[0];
    const float* weight = (const float*)d_in[1];
    const float* bias   = (const float*)d_in[2];
    const float* rw     = (const float*)d_in[3];
    const float* rb     = (const float*)d_in[4];
    float* out = (float*)d_out;

    char* ws = (char*)d_ws;
    u16*   aggw    = (u16*)(ws);                          // 18,874,368 B
    u16*   xt2     = (u16*)(ws + 18874368);               // 35,684,352 B (halo 66x66)
    float* pooled  = (float*)(ws + 54558720);             // 16 KB
    float* aggb    = (float*)(ws + 54558720 + 16384);     // 16 KB

    hipMemsetAsync(pooled, 0, B_*CIN*sizeof(float), stream);
    k_xt   <<<4096, 256, 0, stream>>>(x, xt2, pooled);
    k_aggw <<<COUT, 576, 0, stream>>>(weight, pooled, rw, rb, bias, aggw, aggb);
    k_conv <<<1024, 256, 0, stream>>>(aggw, xt2, aggb, out);
}

// Round 19
// 120.457 us; speedup vs baseline: 1.0574x; 1.0574x over previous
//
#include <hip/hip_runtime.h>
#include <hip/hip_bf16.h>

typedef unsigned short u16;
typedef __attribute__((ext_vector_type(8))) short bf16x8;
typedef __attribute__((ext_vector_type(8))) short short8;
typedef __attribute__((ext_vector_type(4))) float f32x4;

#define B_ 16
#define CIN 256
#define COUT 256
#define NPIX 4096
#define E_ 8
#define HP 66            // halo-padded width/height
#define PPIX (HP*HP)     // 4356 padded pixels per sample
#define KTOT 2304        // 9 * 256
#define NKT2 72          // K-subtiles of 32

__device__ __forceinline__ u16 f2bf(float f){
    union { float f; unsigned int u; } v; v.f = f;
    return (u16)((v.u + 0x7FFFu + ((v.u >> 16) & 1u)) >> 16);
}

__device__ __forceinline__ void gload(const u16* g, u16* l){
    __builtin_amdgcn_global_load_lds(
        (const __attribute__((address_space(1))) unsigned int*)g,
        (__attribute__((address_space(3))) unsigned int*)l, 16, 0, 0);
}

// -------- 1) transpose+convert x -> xt2[b][(y+1)*66+(x+1)][cin] bf16,
//            fused pool + border-zero; coalesced uint4 stores + cvt_pk --------
__global__ void k_xt(const float* __restrict__ x, u16* __restrict__ xt2,
                     float* __restrict__ pooled){
    __shared__ float tile[64][65];
    int bid = blockIdx.x;
    int t = threadIdx.x;

    if (bid < 520){
        int gid = bid*256 + t;
        int u4 = gid & 31;
        int pl = gid >> 5;
        if (pl < B_*260){
            int bb = pl / 260;
            int pi = pl - bb*260;
            int yy, xx;
            if (pi < 66)      { yy = 0;  xx = pi; }
            else if (pi < 132){ yy = 65; xx = pi - 66; }
            else { int q = pi - 132; yy = 1 + (q >> 1); xx = (q & 1) ? 65 : 0; }
            uint4 z = {0u,0u,0u,0u};
            *(uint4*)(xt2 + ((size_t)bb*PPIX + yy*HP + xx)*CIN + u4*8) = z;
        }
    }

    int b = bid >> 8, ct = (bid >> 6) & 3, pt = bid & 63;
    int c0 = ct*64, p0 = pt*64;
    #pragma unroll
    for (int iter = 0; iter < 4; ++iter){
        int idx = t*4 + iter*1024;
        int r = idx >> 6, c4 = idx & 63;
        float4 v = *(const float4*)(x + ((size_t)(b*CIN + c0 + r))*NPIX + p0 + c4);
        tile[r][c4+0] = v.x; tile[r][c4+1] = v.y; tile[r][c4+2] = v.z; tile[r][c4+3] = v.w;
        float rs = v.x + v.y + v.z + v.w;
        #pragma unroll
        for (int off = 1; off < 16; off <<= 1) rs += __shfl_xor(rs, off, 64);
        if ((t & 15) == 0) atomicAdd(&pooled[b*CIN + c0 + r], rs);
    }
    __syncthreads();
    #pragma unroll
    for (int iter = 0; iter < 2; ++iter){
        int unit = t + iter*256;
        int g_l = unit & 7, pr = unit >> 3;
        unsigned int d0, d1, d2, d3;
        asm("v_cvt_pk_bf16_f32 %0, %1, %2" : "=v"(d0)
            : "v"(tile[g_l*8+0][pr]), "v"(tile[g_l*8+1][pr]));
        asm("v_cvt_pk_bf16_f32 %0, %1, %2" : "=v"(d1)
            : "v"(tile[g_l*8+2][pr]), "v"(tile[g_l*8+3][pr]));
        asm("v_cvt_pk_bf16_f32 %0, %1, %2" : "=v"(d2)
            : "v"(tile[g_l*8+4][pr]), "v"(tile[g_l*8+5][pr]));
        asm("v_cvt_pk_bf16_f32 %0, %1, %2" : "=v"(d3)
            : "v"(tile[g_l*8+6][pr]), "v"(tile[g_l*8+7][pr]));
        uint4 o; o.x = d0; o.y = d1; o.z = d2; o.w = d3;
        int p = p0 + pr;
        int yy = p >> 6, xx = p & 63;
        *(uint4*)(xt2 + ((size_t)b*PPIX + (yy+1)*HP + (xx+1))*CIN + c0 + g_l*8) = o;
    }
}

// -------- 2) aggregated weights: 576 threads, batch split across two thread groups --------
__global__ __launch_bounds__(576) void k_aggw(
    const float* __restrict__ weight, const float* __restrict__ pooled,
    const float* __restrict__ rw, const float* __restrict__ rb,
    const float* __restrict__ bias,
    u16* __restrict__ aggw, float* __restrict__ aggb)
{
    __shared__ float wls[E_][2304];
    __shared__ float r_s[B_*E_];
    int o = blockIdx.x, t = threadIdx.x;

    if (t < B_*E_){
        int b = t >> 3, e = t & 7;
        const float4* pp = (const float4*)(pooled + b*CIN);
        const float4* wp = (const float4*)(rw + e*CIN);
        float s = 0.f;
        #pragma unroll
        for (int i = 0; i < 64; ++i){
            float4 a = pp[i], c = wp[i];
            s += a.x*c.x + a.y*c.y + a.z*c.z + a.w*c.w;
        }
        s = s * (1.0f/(float)NPIX) + rb[e];
        r_s[t] = 1.0f/(1.0f + __expf(-s));
    }
    #pragma unroll
    for (int e = 0; e < E_; ++e){
        const float4* src = (const float4*)(weight + ((size_t)(e*COUT + o))*2304);
        float4* dst = (float4*)wls[e];
        dst[t] = src[t];
    }
    __syncthreads();

    if (t < B_){
        float s = 0.f;
        #pragma unroll
        for (int e = 0; e < E_; ++e) s += r_s[t*E_+e]*bias[e*COUT+o];
        aggb[t*COUT + o] = s;
    }

    {
        int grp = (t >= 288);
        int u = t - grp*288;
        int tp = u >> 5, cg = u & 31;
        float w[E_][8];
        #pragma unroll
        for (int e = 0; e < E_; ++e)
            #pragma unroll
            for (int j = 0; j < 8; ++j)
                w[e][j] = wls[e][(cg*8 + j)*9 + tp];

        int b0 = grp*8;
        for (int bb = 0; bb < 8; ++bb){
            int b = b0 + bb;
            float acc[8];
            #pragma unroll
            for (int j = 0; j < 8; ++j) acc[j] = 0.f;
            #pragma unroll
            for (int e = 0; e < E_; ++e){
                float r = r_s[b*E_ + e];
                #pragma unroll
                for (int j = 0; j < 8; ++j) acc[j] += r * w[e][j];
            }
            short8 ov;
            #pragma unroll
            for (int jj = 0; jj < 4; ++jj){
                unsigned int d;
                asm("v_cvt_pk_bf16_f32 %0, %1, %2" : "=v"(d) : "v"(acc[2*jj]), "v"(acc[2*jj+1]));
                ov[2*jj]   = (short)(d & 0xFFFF);
                ov[2*jj+1] = (short)(d >> 16);
            }
            *(short8*)(aggw + (((size_t)(b*COUT + o))*9 + tp)*CIN + cg*8) = ov;
        }
    }
}

// -------- 3) k_conv: 256x256, BK=32, 4 x 32KB buffers (R7 geometry, proven),
//            TWO subtiles per barrier region -> reads(s+1) interleave MFMA(s) --------
__global__ __launch_bounds__(512, 1) void k_conv(
    const u16* __restrict__ aggw, const u16* __restrict__ xt2,
    const float* __restrict__ aggb, float* __restrict__ out)
{
    __shared__ __align__(16) u16 lds[65536];   // 4 bufs x (A 256x32 16KB + B 256x32 16KB)

    int orig = blockIdx.x;
    int bid = (orig & 7)*32 + (orig >> 3);     // bijective XCD swizzle (256 % 8 == 0)

    int b  = bid >> 4;
    int nt = bid & 15;
    int y0 = nt << 2;

    int t = threadIdx.x;
    int lane = t & 63;
    int w = t >> 6;
    int wm = (w >> 2) << 7;      // 0 / 128
    int wn = (w & 3) << 6;       // 0 / 64 / 128 / 192
    int l16 = lane & 15;
    int kh4 = lane >> 4;

    // R7-proven read-side swizzle (0 conflicts measured)
    int ck = ((kh4 ^ ((l16 >> 1) & 3)) << 3);

    // R7-proven staging: thread t -> row sr = t>>2, slot t&3 holds granule (t&3)^((sr>>1)&3)
    int sr  = t >> 2;
    int lc8 = (((t & 3) ^ ((sr >> 1) & 3)) << 3);

    const u16* aS = aggw + (size_t)b*COUT*9*CIN + (size_t)sr*(9*CIN) + lc8;
    const u16* bS = xt2 + ((size_t)b*PPIX + (size_t)(y0 + (sr >> 6))*HP + (sr & 63))*CIN + lc8;

    f32x4 acc[8][4];
    #pragma unroll
    for (int i = 0; i < 8; ++i)
        #pragma unroll
        for (int j = 0; j < 4; ++j){
            f32x4 z = {0.f,0.f,0.f,0.f};
            acc[i][j] = z;
        }

    auto stage = [&](int kt, int bufn){
        int tap = kt >> 3;
        int c0  = (kt & 7) << 5;
        int kh  = tap / 3, kw = tap - kh*3;
        const u16* a0 = aS + tap*CIN + c0;
        const u16* b0 = bS + (kh*HP + kw)*CIN + c0;
        u16* base = lds + bufn*16384 + w*512;
        gload(a0, base);
        gload(a0 + (size_t)128*9*CIN, base + 4096);
        gload(b0, base + 8192);
        gload(b0 + (size_t)2*HP*CIN, base + 12288);
    };

    auto rd = [&](const u16* LA, bf16x8 (&af)[8], bf16x8 (&bv)[4]){
        const u16* LB = LA + 8192;
        #pragma unroll
        for (int mf = 0; mf < 8; ++mf)
            af[mf] = *(const bf16x8*)(LA + (wm + mf*16 + l16)*32 + ck);
        #pragma unroll
        for (int nf = 0; nf < 4; ++nf)
            bv[nf] = *(const bf16x8*)(LB + (wn + nf*16 + l16)*32 + ck);
    };
    auto mma = [&](bf16x8 (&af)[8], bf16x8 (&bv)[4]){
        #pragma unroll
        for (int mf = 0; mf < 8; ++mf)
            #pragma unroll
            for (int nf = 0; nf < 4; ++nf)
                acc[mf][nf] = __builtin_amdgcn_mfma_f32_16x16x32_bf16(
                    af[mf], bv[nf], acc[mf][nf], 0, 0, 0);
    };

    stage(0, 0);
    stage(1, 1);
    __syncthreads();

    for (int s = 0; s < NKT2; s += 2){
        bf16x8 afA[8], bvA[4], afB[8], bvB[4];

        rd(lds + (s & 3)*16384, afA, bvA);          // tile s frags

        if (s + 2 < NKT2) stage(s + 2, (s + 2) & 3);
        if (s + 3 < NKT2) stage(s + 3, (s + 3) & 3);

        rd(lds + ((s + 1) & 3)*16384, afB, bvB);    // tile s+1 frags (independent of mma below)

        mma(afA, bvA);     // compiler interleaves afB/bvB ds_reads under these MFMAs
        mma(afB, bvB);

        __syncthreads();   // drains reads + stages; buffers (s+2)&3,(s+3)&3 ready
    }

    const float* ab = aggb + b*COUT;
    float* outp = out + ((size_t)b*COUT)*NPIX + nt*256;
    #pragma unroll
    for (int mf8 = 0; mf8 < 8; ++mf8){
        #pragma unroll
        for (int v = 0; v < 4; ++v){
            int r = wm + mf8*16 + (kh4 << 2) + v;
            float bias_r = ab[r];
            float* orow = outp + (size_t)r*NPIX;
            #pragma unroll
            for (int nf = 0; nf < 4; ++nf)
                orow[wn + nf*16 + l16] = acc[mf8][nf][v] + bias_r;
        }
    }
}

extern "C" void kernel_launch(void* const* d_in, const int* in_sizes, int n_in,
                              void* d_out, int out_size, void* d_ws, size_t ws_size,
                              hipStream_t stream)
{
    const float* x      = (const float*)d_in[0];
    const float* weight = (const float*)d_in[1];
    const float* bias   = (const float*)d_in[2];
    const float* rw     = (const float*)d_in[3];
    const float* rb     = (const float*)d_in[4];
    float* out = (float*)d_out;

    char* ws = (char*)d_ws;
    u16*   aggw    = (u16*)(ws);                          // 18,874,368 B
    u16*   xt2     = (u16*)(ws + 18874368);               // 35,684,352 B (halo 66x66)
    float* pooled  = (float*)(ws + 54558720);             // 16 KB
    float* aggb    = (float*)(ws + 54558720 + 16384);     // 16 KB

    hipMemsetAsync(pooled, 0, B_*CIN*sizeof(float), stream);
    k_xt   <<<4096, 256, 0, stream>>>(x, xt2, pooled);
    k_aggw <<<COUT, 576, 0, stream>>>(weight, pooled, rw, rb, bias, aggw, aggb);
    k_conv <<<256,  512, 0, stream>>>(aggw, xt2, aggb, out);
}

// Round 20
// 113.098 us; speedup vs baseline: 1.1262x; 1.0651x over previous
//
#include <hip/hip_runtime.h>
#include <hip/hip_bf16.h>

typedef unsigned short u16;
typedef __attribute__((ext_vector_type(8))) short bf16x8;
typedef __attribute__((ext_vector_type(8))) short short8;
typedef __attribute__((ext_vector_type(4))) float f32x4;

#define B_ 16
#define CIN 256
#define COUT 256
#define NPIX 4096
#define E_ 8
#define HP 66            // halo-padded width/height
#define PPIX (HP*HP)     // 4356 padded pixels per sample
#define KTOT 2304        // 9 * 256
#define NKT 36           // K-tiles of 64

__device__ __forceinline__ u16 f2bf(float f){
    union { float f; unsigned int u; } v; v.f = f;
    return (u16)((v.u + 0x7FFFu + ((v.u >> 16) & 1u)) >> 16);
}

__device__ __forceinline__ void gload(const u16* g, u16* l){
    __builtin_amdgcn_global_load_lds(
        (const __attribute__((address_space(1))) unsigned int*)g,
        (__attribute__((address_space(3))) unsigned int*)l, 16, 0, 0);
}

// -------- 1) transpose+convert x -> xt2[b][(y+1)*66+(x+1)][cin] bf16,
//            fused pool + border-zero; coalesced uint4 stores + cvt_pk --------
__global__ void k_xt(const float* __restrict__ x, u16* __restrict__ xt2,
                     float* __restrict__ pooled){
    __shared__ float tile[64][65];
    int bid = blockIdx.x;
    int t = threadIdx.x;

    if (bid < 520){
        int gid = bid*256 + t;
        int u4 = gid & 31;
        int pl = gid >> 5;
        if (pl < B_*260){
            int bb = pl / 260;
            int pi = pl - bb*260;
            int yy, xx;
            if (pi < 66)      { yy = 0;  xx = pi; }
            else if (pi < 132){ yy = 65; xx = pi - 66; }
            else { int q = pi - 132; yy = 1 + (q >> 1); xx = (q & 1) ? 65 : 0; }
            uint4 z = {0u,0u,0u,0u};
            *(uint4*)(xt2 + ((size_t)bb*PPIX + yy*HP + xx)*CIN + u4*8) = z;
        }
    }

    int b = bid >> 8, ct = (bid >> 6) & 3, pt = bid & 63;
    int c0 = ct*64, p0 = pt*64;
    #pragma unroll
    for (int iter = 0; iter < 4; ++iter){
        int idx = t*4 + iter*1024;
        int r = idx >> 6, c4 = idx & 63;
        float4 v = *(const float4*)(x + ((size_t)(b*CIN + c0 + r))*NPIX + p0 + c4);
        tile[r][c4+0] = v.x; tile[r][c4+1] = v.y; tile[r][c4+2] = v.z; tile[r][c4+3] = v.w;
        float rs = v.x + v.y + v.z + v.w;
        #pragma unroll
        for (int off = 1; off < 16; off <<= 1) rs += __shfl_xor(rs, off, 64);
        if ((t & 15) == 0) atomicAdd(&pooled[b*CIN + c0 + r], rs);
    }
    __syncthreads();
    #pragma unroll
    for (int iter = 0; iter < 2; ++iter){
        int unit = t + iter*256;
        int g_l = unit & 7, pr = unit >> 3;
        unsigned int d0, d1, d2, d3;
        asm("v_cvt_pk_bf16_f32 %0, %1, %2" : "=v"(d0)
            : "v"(tile[g_l*8+0][pr]), "v"(tile[g_l*8+1][pr]));
        asm("v_cvt_pk_bf16_f32 %0, %1, %2" : "=v"(d1)
            : "v"(tile[g_l*8+2][pr]), "v"(tile[g_l*8+3][pr]));
        asm("v_cvt_pk_bf16_f32 %0, %1, %2" : "=v"(d2)
            : "v"(tile[g_l*8+4][pr]), "v"(tile[g_l*8+5][pr]));
        asm("v_cvt_pk_bf16_f32 %0, %1, %2" : "=v"(d3)
            : "v"(tile[g_l*8+6][pr]), "v"(tile[g_l*8+7][pr]));
        uint4 o; o.x = d0; o.y = d1; o.z = d2; o.w = d3;
        int p = p0 + pr;
        int yy = p >> 6, xx = p & 63;
        *(uint4*)(xt2 + ((size_t)b*PPIX + (yy+1)*HP + (xx+1))*CIN + c0 + g_l*8) = o;
    }
}

// -------- 2) aggregated weights: 576 threads, batch split across two thread groups --------
__global__ __launch_bounds__(576) void k_aggw(
    const float* __restrict__ weight, const float* __restrict__ pooled,
    const float* __restrict__ rw, const float* __restrict__ rb,
    const float* __restrict__ bias,
    u16* __restrict__ aggw, float* __restrict__ aggb)
{
    __shared__ float wls[E_][2304];
    __shared__ float r_s[B_*E_];
    int o = blockIdx.x, t = threadIdx.x;

    if (t < B_*E_){
        int b = t >> 3, e = t & 7;
        const float4* pp = (const float4*)(pooled + b*CIN);
        const float4* wp = (const float4*)(rw + e*CIN);
        float s = 0.f;
        #pragma unroll
        for (int i = 0; i < 64; ++i){
            float4 a = pp[i], c = wp[i];
            s += a.x*c.x + a.y*c.y + a.z*c.z + a.w*c.w;
        }
        s = s * (1.0f/(float)NPIX) + rb[e];
        r_s[t] = 1.0f/(1.0f + __expf(-s));
    }
    #pragma unroll
    for (int e = 0; e < E_; ++e){
        const float4* src = (const float4*)(weight + ((size_t)(e*COUT + o))*2304);
        float4* dst = (float4*)wls[e];
        dst[t] = src[t];
    }
    __syncthreads();

    if (t < B_){
        float s = 0.f;
        #pragma unroll
        for (int e = 0; e < E_; ++e) s += r_s[t*E_+e]*bias[e*COUT+o];
        aggb[t*COUT + o] = s;
    }

    {
        int grp = (t >= 288);
        int u = t - grp*288;
        int tp = u >> 5, cg = u & 31;
        float w[E_][8];
        #pragma unroll
        for (int e = 0; e < E_; ++e)
            #pragma unroll
            for (int j = 0; j < 8; ++j)
                w[e][j] = wls[e][(cg*8 + j)*9 + tp];

        int b0 = grp*8;
        for (int bb = 0; bb < 8; ++bb){
            int b = b0 + bb;
            float acc[8];
            #pragma unroll
            for (int j = 0; j < 8; ++j) acc[j] = 0.f;
            #pragma unroll
            for (int e = 0; e < E_; ++e){
                float r = r_s[b*E_ + e];
                #pragma unroll
                for (int j = 0; j < 8; ++j) acc[j] += r * w[e][j];
            }
            short8 ov;
            #pragma unroll
            for (int jj = 0; jj < 4; ++jj){
                unsigned int d;
                asm("v_cvt_pk_bf16_f32 %0, %1, %2" : "=v"(d) : "v"(acc[2*jj]), "v"(acc[2*jj+1]));
                ov[2*jj]   = (short)(d & 0xFFFF);
                ov[2*jj+1] = (short)(d >> 16);
            }
            *(short8*)(aggw + (((size_t)(b*COUT + o))*9 + tp)*CIN + cg*8) = ov;
        }
    }
}

// -------- 3) k_conv: R16 (best measured: 72.0 us) — 256x256, BK=64, dbuf,
//            proven XOR swizzle, no setprio, compiler-scheduled waits --------
__global__ __launch_bounds__(512, 2) void k_conv(
    const u16* __restrict__ aggw, const u16* __restrict__ xt2,
    const float* __restrict__ aggb, float* __restrict__ out)
{
    __shared__ __align__(16) u16 lds[65536];   // 2 buf x (A 256x64 + B 256x64) bf16

    int orig = blockIdx.x;
    int bid = (orig & 7)*32 + (orig >> 3);     // bijective XCD swizzle

    int b  = bid >> 4;
    int nt = bid & 15;
    int y0 = nt << 2;

    int t = threadIdx.x;
    int lane = t & 63;
    int w = t >> 6;
    int wm = (w >> 2) << 7;
    int wn = (w & 3) << 6;
    int l16 = lane & 15;
    int kh4 = lane >> 4;
    int sw  = l16 & 7;

    int tr = t >> 3;
    int tc = t & 7;
    int sc = tc ^ (tr & 7);

    const u16* aSrc = aggw + (size_t)b*COUT*9*CIN + (size_t)tr*KTOT + sc*8;
    const u16* bSrc = xt2 + ((size_t)b*PPIX + (size_t)y0*HP + tr)*CIN + sc*8;

    f32x4 acc[8][4];
    #pragma unroll
    for (int i = 0; i < 8; ++i)
        #pragma unroll
        for (int j = 0; j < 4; ++j){
            f32x4 z = {0.f,0.f,0.f,0.f};
            acc[i][j] = z;
        }

    auto stage = [&](int kt, int bufn){
        int tap = kt >> 2;
        int c0  = (kt & 3) << 6;
        int kh  = tap / 3, kw = tap - kh*3;
        const u16* a0 = aSrc + tap*CIN + c0;
        const u16* b0 = bSrc + (kh*HP + kw)*CIN + c0;
        u16* dA = lds + bufn*32768 + w*512;
        u16* dB = dA + 16384;
        #pragma unroll
        for (int i = 0; i < 4; ++i)
            gload(a0 + (size_t)i*64*KTOT, dA + i*4096);
        #pragma unroll
        for (int i = 0; i < 4; ++i)
            gload(b0 + (size_t)i*HP*CIN, dB + i*4096);
    };

    int ck0 = ((kh4    ) ^ sw) * 8;
    int ck1 = ((kh4 | 4) ^ sw) * 8;

    stage(0, 0);
    __syncthreads();

    int buf = 0;
    #pragma unroll 2
    for (int kt = 0; kt < NKT; ++kt){
        const u16* LA = lds + buf*32768;
        const u16* LB = LA + 16384;

        bf16x8 af[2][4][2];    // [qm][mf][khalf]
        bf16x8 bfr[2][2][2];   // [qn][nf][khalf]

        #pragma unroll
        for (int mf = 0; mf < 4; ++mf){
            int ro = (wm + mf*16 + l16) * 64;
            af[0][mf][0] = *(const bf16x8*)(LA + ro + ck0);
            af[0][mf][1] = *(const bf16x8*)(LA + ro + ck1);
        }
        #pragma unroll
        for (int nf = 0; nf < 2; ++nf){
            int ro = (wn + nf*16 + l16) * 64;
            bfr[0][nf][0] = *(const bf16x8*)(LB + ro + ck0);
            bfr[0][nf][1] = *(const bf16x8*)(LB + ro + ck1);
        }

        if (kt < NKT-1) stage(kt+1, buf^1);

        #pragma unroll
        for (int nf = 0; nf < 2; ++nf){
            int ro = (wn + 32 + nf*16 + l16) * 64;
            bfr[1][nf][0] = *(const bf16x8*)(LB + ro + ck0);
            bfr[1][nf][1] = *(const bf16x8*)(LB + ro + ck1);
        }
        #pragma unroll
        for (int mf = 0; mf < 4; ++mf){
            int ro = (wm + 64 + mf*16 + l16) * 64;
            af[1][mf][0] = *(const bf16x8*)(LA + ro + ck0);
            af[1][mf][1] = *(const bf16x8*)(LA + ro + ck1);
        }

        #pragma unroll
        for (int qm = 0; qm < 2; ++qm)
            #pragma unroll
            for (int qn = 0; qn < 2; ++qn){
                #pragma unroll
                for (int mf = 0; mf < 4; ++mf)
                    #pragma unroll
                    for (int nf = 0; nf < 2; ++nf){
                        acc[qm*4+mf][qn*2+nf] = __builtin_amdgcn_mfma_f32_16x16x32_bf16(
                            af[qm][mf][0], bfr[qn][nf][0], acc[qm*4+mf][qn*2+nf], 0, 0, 0);
                        acc[qm*4+mf][qn*2+nf] = __builtin_amdgcn_mfma_f32_16x16x32_bf16(
                            af[qm][mf][1], bfr[qn][nf][1], acc[qm*4+mf][qn*2+nf], 0, 0, 0);
                    }
            }

        __syncthreads();
        buf ^= 1;
    }

    const float* ab = aggb + b*COUT;
    float* outp = out + ((size_t)b*COUT)*NPIX + nt*256;
    #pragma unroll
    for (int mf8 = 0; mf8 < 8; ++mf8){
        #pragma unroll
        for (int v = 0; v < 4; ++v){
            int r = wm + mf8*16 + (kh4 << 2) + v;
            float bias_r = ab[r];
            float* orow = outp + (size_t)r*NPIX;
            #pragma unroll
            for (int nf = 0; nf < 4; ++nf)
                orow[wn + nf*16 + l16] = acc[mf8][nf][v] + bias_r;
        }
    }
}

extern "C" void kernel_launch(void* const* d_in, const int* in_sizes, int n_in,
                              void* d_out, int out_size, void* d_ws, size_t ws_size,
                              hipStream_t stream)
{
    const float* x      = (const float*)d_in[0];
    const float* weight = (const float*)d_in[1];
    const float* bias   = (const float*)d_in[2];
    const float* rw     = (const float*)d_in[3];
    const float* rb     = (const float*)d_in[4];
    float* out = (float*)d_out;

    char* ws = (char*)d_ws;
    u16*   aggw    = (u16*)(ws);                          // 18,874,368 B
    u16*   xt2     = (u16*)(ws + 18874368);               // 35,684,352 B (halo 66x66)
    float* pooled  = (float*)(ws + 54558720);             // 16 KB
    float* aggb    = (float*)(ws + 54558720 + 16384);     // 16 KB

    hipMemsetAsync(pooled, 0, B_*CIN*sizeof(float), stream);
    k_xt   <<<4096, 256, 0, stream>>>(x, xt2, pooled);
    k_aggw <<<COUT, 576, 0, stream>>>(weight, pooled, rw, rb, bias, aggw, aggb);
    k_conv <<<256,  512, 0, stream>>>(aggw, xt2, aggb, out);
}